// Round 1
// baseline (622.077 us; speedup 1.0000x reference)
//
#include <hip/hip_runtime.h>

using half_t = _Float16;
using half8  = __attribute__((ext_vector_type(8))) _Float16;
using half4  = __attribute__((ext_vector_type(4))) _Float16;
using f32x4  = __attribute__((ext_vector_type(4))) float;

#define MFMA(a, b, c) __builtin_amdgcn_mfma_f32_16x16x32_f16((a), (b), (c), 0, 0, 0)

// async global->LDS, 16 B per lane. LDS dest = wave-uniform base + lane*16.
#define GLL16(g, l)                                                     \
  __builtin_amdgcn_global_load_lds(                                     \
      (__attribute__((address_space(1))) void*)(g),                     \
      (__attribute__((address_space(3))) void*)(l), 16, 0, 0)

__device__ __forceinline__ half8 ld8(const half_t* p) { return *(const half8*)p; }

// ---------------------------------------------------------------- convert
__global__ void cvt_f32_f16(const float* __restrict__ src, half_t* __restrict__ dst, int n4) {
  int i = blockIdx.x * blockDim.x + threadIdx.x;
  if (i < n4) {
    f32x4 v = ((const f32x4*)src)[i];
    half4 h;
    h[0] = (half_t)v[0]; h[1] = (half_t)v[1]; h[2] = (half_t)v[2]; h[3] = (half_t)v[3];
    ((half4*)dst)[i] = h;
  }
}

// ---------------------------------------------------------------- GEMM (C = A * Bt^T), m97 structure
// EPI 0: qh  -> (B,H,Lq,D) f16          (M=4096, N=1024)
// EPI 1: kv  -> k (B,H,Lkv,D), vT (B,H,D,Lkv) f16   (M=8192, N=2048)
// EPI 2: out -> fp32 + bias             (M=4096, N=1024)
template <int EPI>
__global__ __launch_bounds__(256) void gemm_kernel(
    const half_t* __restrict__ A, const half_t* __restrict__ Bt,
    int M, int N, int K,
    half_t* __restrict__ oh, half_t* __restrict__ ov,
    float* __restrict__ of, const float* __restrict__ bias) {
  __shared__ alignas(16) half_t sA[128 * 32];
  __shared__ alignas(16) half_t sB[128 * 32];
  const int tid  = threadIdx.x;
  const int lane = tid & 63;
  const int w    = tid >> 6;
  const int c    = lane & 15;
  const int quad = lane >> 4;
  const int m0 = blockIdx.y * 128;
  const int n0 = blockIdx.x * 128;
  const int wm = (w & 1) * 64;
  const int wn = (w >> 1) * 64;

  f32x4 acc[4][4] = {};

  const int srow = tid >> 2;          // staging row (0..63), +64 on 2nd round
  const int scol = (tid & 3) * 8;     // half-offset within 32-wide row
  const half_t* Ag = A + (size_t)(m0 + srow) * K + scol;
  const half_t* Bg = Bt + (size_t)(n0 + srow) * K + scol;

  for (int k0 = 0; k0 < K; k0 += 32) {
    GLL16(Ag + k0,            sA + tid * 8);
    GLL16(Ag + k0 + 64 * K,   sA + tid * 8 + 2048);
    GLL16(Bg + k0,            sB + tid * 8);
    GLL16(Bg + k0 + 64 * K,   sB + tid * 8 + 2048);
    __syncthreads();
    half8 a[4], b[4];
#pragma unroll
    for (int i = 0; i < 4; ++i) a[i] = ld8(&sA[(wm + i * 16 + c) * 32 + quad * 8]);
#pragma unroll
    for (int j = 0; j < 4; ++j) b[j] = ld8(&sB[(wn + j * 16 + c) * 32 + quad * 8]);
#pragma unroll
    for (int i = 0; i < 4; ++i)
#pragma unroll
      for (int j = 0; j < 4; ++j) acc[i][j] = MFMA(a[i], b[j], acc[i][j]);
    __syncthreads();
  }

  // epilogue: C element (m = m0+wm+i*16+quad*4+r, n = n0+wn+j*16+c) = acc[i][j][r]
#pragma unroll
  for (int i = 0; i < 4; ++i) {
    const int mbase = m0 + wm + i * 16 + quad * 4;
#pragma unroll
    for (int j = 0; j < 4; ++j) {
      const int n = n0 + wn + j * 16 + c;
      if (EPI == 0) {
        const int bb = mbase >> 10, qi = mbase & 1023;
        const int hh = n >> 6, d = n & 63;
        half_t* p = oh + (((size_t)(bb * 16 + hh) * 1024 + qi) * 64 + d);
#pragma unroll
        for (int r = 0; r < 4; ++r) p[(size_t)r * 64] = (half_t)acc[i][j][r];
      } else if (EPI == 1) {
        const int bb = mbase >> 11, kvi = mbase & 2047;
        if (n < 1024) {
          const int hh = n >> 6, d = n & 63;
          half_t* p = oh + (((size_t)(bb * 16 + hh) * 2048 + kvi) * 64 + d);
#pragma unroll
          for (int r = 0; r < 4; ++r) p[(size_t)r * 64] = (half_t)acc[i][j][r];
        } else {
          const int nn = n - 1024;
          const int hh = nn >> 6, d = nn & 63;
          half4 hv;
#pragma unroll
          for (int r = 0; r < 4; ++r) hv[r] = (half_t)acc[i][j][r];
          *(half4*)&ov[((size_t)(bb * 16 + hh) * 64 + d) * 2048 + kvi] = hv;
        }
      } else {
        const float bv = bias[n];
#pragma unroll
        for (int r = 0; r < 4; ++r) of[(size_t)(mbase + r) * N + n] = acc[i][j][r] + bv;
      }
    }
  }
}

// ---------------------------------------------------------------- flash attention
// grid: ((b*16+h)*16 + qtile), 256 threads (4 waves), 64 q-rows/block, 16 q-rows/wave
__global__ __launch_bounds__(256) void attn_kernel(
    const half_t* __restrict__ qh, const half_t* __restrict__ kk,
    const half_t* __restrict__ vt, const float* __restrict__ pos,
    half_t* __restrict__ xout) {
  __shared__ alignas(16) half_t Qs[64 * 72];
  __shared__ alignas(16) half_t Ks[64 * 72];
  __shared__ alignas(16) half_t Vs[64 * 72];   // vT tile: [d][kv]
  __shared__ alignas(16) half_t Ps[4 * 16 * 72];
  const int tid  = threadIdx.x;
  const int lane = tid & 63;
  const int w    = tid >> 6;
  const int c    = lane & 15;
  const int quad = lane >> 4;
  const int bh = blockIdx.x >> 4;
  const int q0 = (blockIdx.x & 15) << 6;
  const int b  = bh >> 4;
  const int h  = bh & 15;
  const float LOG2E = 1.4426950408889634f;

  { // stage Q (64x64) once
    const half_t* qg = qh + (((size_t)bh << 10) + q0) * 64;
#pragma unroll
    for (int r2 = 0; r2 < 2; ++r2) {
      const int off = tid * 8 + r2 * 2048;
      const int row = off >> 6, col = off & 63;
      *(half8*)&Qs[row * 72 + col] = *(const half8*)&qg[row * 64 + col];
    }
  }

  f32x4 o[4] = {};
  float m_run[4] = {-1e30f, -1e30f, -1e30f, -1e30f};
  float l_run[4] = {0.f, 0.f, 0.f, 0.f};

  const half_t* kg = kk + ((size_t)bh * 2048) * 64;
  const half_t* vg = vt + ((size_t)bh * 64) * 2048;
  const float*  pg = pos + (((size_t)bh << 10) + q0 + w * 16) * 1024;
  half_t* Pw = Ps + w * 16 * 72;

  for (int kv0 = 0; kv0 < 2048; kv0 += 64) {
    __syncthreads();  // prev iter's frag reads done before restaging
#pragma unroll
    for (int r2 = 0; r2 < 2; ++r2) {
      const int off = tid * 8 + r2 * 2048;
      const int row = off >> 6, col = off & 63;
      *(half8*)&Ks[row * 72 + col] = *(const half8*)&kg[(size_t)(kv0 + row) * 64 + col];
      *(half8*)&Vs[row * 72 + col] = *(const half8*)&vg[(size_t)row * 2048 + kv0 + col];
    }
    __syncthreads();

    // S = Q K^T  (16 q-rows x 64 kv), K-dim = D = 64 -> 2 MFMAs per 16-kv tile
    const half8 aq0 = ld8(&Qs[(w * 16 + c) * 72 + quad * 8]);
    const half8 aq1 = ld8(&Qs[(w * 16 + c) * 72 + 32 + quad * 8]);
    f32x4 s[4];
#pragma unroll
    for (int t = 0; t < 4; ++t) {
      const half8 bk0 = ld8(&Ks[(t * 16 + c) * 72 + quad * 8]);
      const half8 bk1 = ld8(&Ks[(t * 16 + c) * 72 + 32 + quad * 8]);
      f32x4 z = {};
      z = MFMA(aq0, bk0, z);
      z = MFMA(aq1, bk1, z);
      s[t] = z;
    }

    float lg[4][4];
    if (kv0 < 1024) {
#pragma unroll
      for (int t = 0; t < 4; ++t)
#pragma unroll
        for (int r = 0; r < 4; ++r)
          lg[t][r] = s[t][r] * 0.125f + pg[(size_t)(quad * 4 + r) * 1024 + kv0 + t * 16 + c];
    } else {
#pragma unroll
      for (int t = 0; t < 4; ++t)
#pragma unroll
        for (int r = 0; r < 4; ++r) lg[t][r] = s[t][r] * 0.125f;
    }

    // online softmax; row (quad*4+r) lives in the 16-lane quad-group -> shfl width 16
    float pvv[4][4];
#pragma unroll
    for (int r = 0; r < 4; ++r) {
      float mx = fmaxf(fmaxf(lg[0][r], lg[1][r]), fmaxf(lg[2][r], lg[3][r]));
      mx = fmaxf(mx, __shfl_xor(mx, 1, 16));
      mx = fmaxf(mx, __shfl_xor(mx, 2, 16));
      mx = fmaxf(mx, __shfl_xor(mx, 4, 16));
      mx = fmaxf(mx, __shfl_xor(mx, 8, 16));
      const float mnew  = fmaxf(m_run[r], mx);
      const float alpha = exp2f((m_run[r] - mnew) * LOG2E);
      float rs = 0.f;
#pragma unroll
      for (int t = 0; t < 4; ++t) {
        const float p = exp2f((lg[t][r] - mnew) * LOG2E);
        pvv[t][r] = p;
        rs += p;
      }
      rs += __shfl_xor(rs, 1, 16);
      rs += __shfl_xor(rs, 2, 16);
      rs += __shfl_xor(rs, 4, 16);
      rs += __shfl_xor(rs, 8, 16);
      l_run[r] = l_run[r] * alpha + rs;
      m_run[r] = mnew;
#pragma unroll
      for (int jd = 0; jd < 4; ++jd) o[jd][r] *= alpha;
    }

    // P: C/D layout -> LDS -> A-operand layout (m120-verified round trip)
#pragma unroll
    for (int t = 0; t < 4; ++t)
#pragma unroll
      for (int r = 0; r < 4; ++r)
        Pw[(quad * 4 + r) * 72 + t * 16 + c] = (half_t)pvv[t][r];
    __syncthreads();

    // O += P V   (A = P[16 x 64kv], B = V[64kv x 64d] via vT tile)
#pragma unroll
    for (int hk = 0; hk < 2; ++hk) {
      const half8 ap = ld8(&Pw[c * 72 + hk * 32 + quad * 8]);
#pragma unroll
      for (int jd = 0; jd < 4; ++jd) {
        const half8 bv = ld8(&Vs[(jd * 16 + c) * 72 + hk * 32 + quad * 8]);
        o[jd] = MFMA(ap, bv, o[jd]);
      }
    }
  }

  // x[b, q, h*64+d] = O / l
#pragma unroll
  for (int jd = 0; jd < 4; ++jd)
#pragma unroll
    for (int r = 0; r < 4; ++r) {
      const int qrow = q0 + w * 16 + quad * 4 + r;
      const int d    = jd * 16 + c;
      xout[((size_t)b * 1024 + qrow) * 1024 + h * 64 + d] = (half_t)(o[jd][r] / l_run[r]);
    }
}

// ---------------------------------------------------------------- launch
extern "C" void kernel_launch(void* const* d_in, const int* in_sizes, int n_in,
                              void* d_out, int out_size, void* d_ws, size_t ws_size,
                              hipStream_t stream) {
  const float* q   = (const float*)d_in[0];
  const float* kv  = (const float*)d_in[1];
  const float* pos = (const float*)d_in[2];
  const float* qw  = (const float*)d_in[3];
  const float* kvw = (const float*)d_in[4];
  const float* pw  = (const float*)d_in[5];
  const float* pb  = (const float*)d_in[6];
  float* out = (float*)d_out;

  char* ws = (char*)d_ws;
  half_t* qf   = (half_t*)(ws);                          //  8 MB  q fp16
  half_t* kvf  = (half_t*)(ws + (size_t)(8)  * 1048576); // 16 MB  kv fp16
  half_t* qwf  = (half_t*)(ws + (size_t)(24) * 1048576); //  2 MB
  half_t* kvwf = (half_t*)(ws + (size_t)(26) * 1048576); //  4 MB
  half_t* pwf  = (half_t*)(ws + (size_t)(30) * 1048576); //  2 MB
  half_t* qh   = (half_t*)(ws + (size_t)(32) * 1048576); //  8 MB  (B,H,Lq,D)
  half_t* kk   = (half_t*)(ws + (size_t)(40) * 1048576); // 16 MB  (B,H,Lkv,D)
  half_t* vt   = (half_t*)(ws + (size_t)(56) * 1048576); // 16 MB  (B,H,D,Lkv)
  half_t* xb   = (half_t*)(ws + (size_t)(72) * 1048576); //  8 MB  (B,Lq,C)

  auto cvt = [&](const float* s, half_t* d, int n) {
    cvt_f32_f16<<<n / 1024, 256, 0, stream>>>(s, d, n / 4);
  };
  cvt(q,   qf,   4 * 1024 * 1024);
  cvt(kv,  kvf,  4 * 2048 * 1024);
  cvt(qw,  qwf,  1024 * 1024);
  cvt(kvw, kvwf, 2048 * 1024);
  cvt(pw,  pwf,  1024 * 1024);

  gemm_kernel<0><<<dim3(1024 / 128, 4096 / 128), 256, 0, stream>>>(
      qf, qwf, 4096, 1024, 1024, qh, nullptr, nullptr, nullptr);
  gemm_kernel<1><<<dim3(2048 / 128, 8192 / 128), 256, 0, stream>>>(
      kvf, kvwf, 8192, 2048, 1024, kk, vt, nullptr, nullptr);
  attn_kernel<<<4 * 16 * 16, 256, 0, stream>>>(qh, kk, vt, pos, xb);
  gemm_kernel<2><<<dim3(1024 / 128, 4096 / 128), 256, 0, stream>>>(
      xb, pwf, 4096, 1024, 1024, nullptr, nullptr, out, pb);
}